// Round 1
// 174.522 us; speedup vs baseline: 1.0396x; 1.0396x over previous
//
#include <hip/hip_runtime.h>
#include <hip/hip_bf16.h>
#include <math.h>

#define N_TOT 1024
#define C_DIM 4096
#define T_MARGIN 3e-4f   // coarse fp16 cosine err sigma ~6e-6; 3e-4 = ~50 sigma

typedef __attribute__((ext_vector_type(8))) _Float16 half8;
typedef __attribute__((ext_vector_type(8))) unsigned short ushort8;
typedef __attribute__((ext_vector_type(8))) char schar8;
typedef __attribute__((ext_vector_type(4))) float floatx4;

__device__ inline unsigned short f2h(float v) {
    _Float16 h = (_Float16)v;
    return __builtin_bit_cast(unsigned short, h);
}
__device__ inline float h2f(unsigned short u) {
    return (float)__builtin_bit_cast(_Float16, u);
}
// int8 residual with exponent borrowed from the fp16 hi part (err ~ulp/480).
__device__ inline char lo_enc(float v, unsigned short h) {
    int e = (h >> 10) & 31;
    float lo = v - h2f(h);
    float q = rintf(lo * 240.0f * __uint_as_float((unsigned)(152 - e) << 23));
    q = fmaxf(-127.0f, fminf(127.0f, q));
    return (char)(int)q;
}
__device__ inline float lo_dec(char q, unsigned short h) {
    int e = (h >> 10) & 31;
    return (float)q * __uint_as_float((unsigned)(e + 102) << 23) * (1.0f / 240.0f);
}

// lexicographic (value desc, index asc) insert into a sorted top-2 pair
__device__ inline void ins2(float v, int s, float& v1, int& s1, float& v2, int& s2) {
    if (v > v1 || (v == v1 && s < s1)) { v2 = v1; s2 = s1; v1 = v; s1 = s; }
    else if (v > v2 || (v == v2 && s < s2)) { v2 = v; s2 = s; }
}

// ---------------------------------------------------------------------------
// split+transpose+norms: X (C,N) fp32 -> Xhi[n][c] fp16, Xlo[n][c] int8;
// normX[n] += sum_c x^2 (atomic, pre-zeroed). Block (0,0,0) additionally
// computes the flag compaction (colidx, n0). grid (64, 16, 2).
__global__ __launch_bounds__(256) void split_norms(const float* __restrict__ G,
                                                   const float* __restrict__ Kn,
                                                   const float* __restrict__ flag,
                                                   unsigned short* __restrict__ Phi,
                                                   char* __restrict__ Plo,
                                                   unsigned short* __restrict__ Khi,
                                                   char* __restrict__ Klo,
                                                   float* __restrict__ normP,
                                                   float* __restrict__ normK,
                                                   int* __restrict__ colidx,
                                                   int* __restrict__ n0p) {
    const int z = blockIdx.z;
    const float* X = z ? Kn : G;
    unsigned short* Xhi = z ? Khi : Phi;
    char* Xlo = z ? Klo : Plo;
    float* normX = z ? normK : normP;

    __shared__ float tile[64 * 65];
    __shared__ float np[256];
    const int t  = threadIdx.x;
    const int c0 = blockIdx.x * 64;
    const int n0 = blockIdx.y * 64;

    float s2 = 0.0f;
    #pragma unroll
    for (int s = 0; s < 16; s++) {
        int c_loc = s * 4 + (t >> 6);
        int n_loc = t & 63;
        float v = X[(c0 + c_loc) * N_TOT + n0 + n_loc];
        tile[c_loc * 65 + n_loc] = v;
        s2 = fmaf(v, v, s2);
    }
    np[t] = s2;
    __syncthreads();

    if (t < 64) {
        float tot = np[t] + np[t + 64] + np[t + 128] + np[t + 192];
        atomicAdd(&normX[n0 + t], tot);
    }

    #pragma unroll
    for (int s = 0; s < 4; s++) {
        int n_loc = s * 16 + (t >> 4);
        int c4    = (t & 15) * 4;
        unsigned short h[4]; char l[4];
        #pragma unroll
        for (int e = 0; e < 4; e++) {
            float v = tile[(c4 + e) * 65 + n_loc];
            h[e] = f2h(v);
            l[e] = lo_enc(v, h[e]);
        }
        size_t base = (size_t)(n0 + n_loc) * C_DIM + c0 + c4;
        *(ushort4*)&Xhi[base] = make_ushort4(h[0], h[1], h[2], h[3]);
        *(char4*)&Xlo[base]   = make_char4(l[0], l[1], l[2], l[3]);
    }

    // ---- embedded flag scan (block (0,0,0) only; block-uniform branch) ----
    if (blockIdx.x == 0 && blockIdx.y == 0 && blockIdx.z == 0) {
        __shared__ int cz[256];
        __shared__ int co[256];
        float4 fv = *(const float4*)&flag[4 * t];
        int f[4] = {fv.x == 0.0f, fv.y == 0.0f, fv.z == 0.0f, fv.w == 0.0f};
        int nz = f[0] + f[1] + f[2] + f[3];
        cz[t] = nz; co[t] = 4 - nz;
        __syncthreads();
        for (int off = 1; off < 256; off <<= 1) {
            int vz = (t >= off) ? cz[t - off] : 0;
            int vo = (t >= off) ? co[t - off] : 0;
            __syncthreads();
            cz[t] += vz; co[t] += vo;
            __syncthreads();
        }
        const int fn0 = cz[255];
        int zs = cz[t] - nz;
        int os = fn0 + co[t] - (4 - nz);
        #pragma unroll
        for (int e = 0; e < 4; e++) {
            int j = 4 * t + e;
            if (f[e]) colidx[zs++] = j;
            else      colidx[os++] = j;
        }
        if (t == 0) *n0p = fn0;
    }
}

// ---------------------------------------------------------------------------
// coarse fp16 MFMA GEMM vs virtually-compacted B (slot s -> row colidx[s] of
// (s<n0 ? K : P)). 64x128 tile, BK=64, K-split 8 -> grid (16,8,8) = 1024
// blocks, 24 KB LDS, 4 blocks/CU. PLAIN STORES to per-z partial planes
// (each element written once -> no atomics, no zeroing).
__global__ __launch_bounds__(256, 4) void gemm_coarse(const unsigned short* __restrict__ Phi,
                                                      const unsigned short* __restrict__ Khi,
                                                      const int* __restrict__ colidx,
                                                      const int* __restrict__ n0p,
                                                      float* __restrict__ dotPart) {
    __shared__ unsigned short sA[64 * 64];    // 8 KB
    __shared__ unsigned short sB[128 * 64];   // 16 KB

    const int t    = threadIdx.x;
    const int wave = t >> 6, lane = t & 63;
    const int wm   = wave >> 1, wn = wave & 1;
    const int quad = lane >> 4, lrow = lane & 15;
    const int ib = blockIdx.x * 64, jb = blockIdx.y * 128;
    const int bz = blockIdx.z;
    const int k_beg = bz * 512;
    const int n0 = *n0p;

    const int srow = t >> 3;            // 0..31
    const int g    = (t & 7) ^ (srow & 7);

    const unsigned short* gA[2];
    gA[0] = Phi + (size_t)(ib + srow) * C_DIM + g * 8;
    gA[1] = gA[0] + (size_t)32 * C_DIM;
    const unsigned short* gB[4];
    #pragma unroll
    for (int q = 0; q < 4; q++) {
        int s = jb + q * 32 + srow;
        int row = colidx[s];
        const unsigned short* src = (s < n0) ? Khi : Phi;
        gB[q] = src + (size_t)row * C_DIM + g * 8;
    }

    floatx4 acc[2][4] = {};

    for (int k0 = k_beg; k0 < k_beg + 512; k0 += 64) {
        #pragma unroll
        for (int q = 0; q < 2; q++)
            __builtin_amdgcn_global_load_lds(
                (const __attribute__((address_space(1))) void*)(gA[q] + k0),
                (__attribute__((address_space(3))) void*)((char*)sA + q * 4096 + t * 16), 16, 0, 0);
        #pragma unroll
        for (int q = 0; q < 4; q++)
            __builtin_amdgcn_global_load_lds(
                (const __attribute__((address_space(1))) void*)(gB[q] + k0),
                (__attribute__((address_space(3))) void*)((char*)sB + q * 4096 + t * 16), 16, 0, 0);
        __syncthreads();

        #pragma unroll
        for (int kk = 0; kk < 2; kk++) {
            const int gk = kk * 4 + quad;
            half8 a[2], b[4];
            #pragma unroll
            for (int ti = 0; ti < 2; ti++) {
                int m = wm * 32 + ti * 16 + lrow;
                a[ti] = *(const half8*)&sA[m * 64 + ((gk ^ (m & 7)) << 3)];
            }
            #pragma unroll
            for (int tj = 0; tj < 4; tj++) {
                int n = wn * 64 + tj * 16 + lrow;
                b[tj] = *(const half8*)&sB[n * 64 + ((gk ^ (n & 7)) << 3)];
            }
            #pragma unroll
            for (int ti = 0; ti < 2; ti++)
                #pragma unroll
                for (int tj = 0; tj < 4; tj++)
                    acc[ti][tj] = __builtin_amdgcn_mfma_f32_16x16x32_f16(a[ti], b[tj], acc[ti][tj], 0, 0, 0);
        }
        __syncthreads();
    }

    // plain stores into this z's private plane. C/D: col=lane&15, row=quad*4+reg
    float* outp = dotPart + ((size_t)bz << 20);
    #pragma unroll
    for (int tj = 0; tj < 4; tj++) {
        int j = jb + wn * 64 + tj * 16 + lrow;
        #pragma unroll
        for (int ti = 0; ti < 2; ti++) {
            #pragma unroll
            for (int reg = 0; reg < 4; reg++) {
                int i = ib + wm * 32 + ti * 16 + quad * 4 + reg;
                outp[i * N_TOT + j] = acc[ti][tj][reg];
            }
        }
    }
}

// ---------------------------------------------------------------------------
// one block per row: sum 8 partial planes, coarse cosines, SINGLE-PASS top-2
// per partition (wave butterfly + cross-wave merge, 2 barriers), threshold
// ballot for the candidate set (all slots within T_MARGIN of coarse m2),
// exact refine only of those candidates on untrusted rows. grid (1024).
//
// Soundness: |exact - coarse| <= T_MARGIN/2 (same assumption as the margin
// test). Any slot with coarse <= m2 - T_MARGIN has exact < exact(m2-slot),
// so the candidate set provably contains the exact top-2.
__global__ __launch_bounds__(256) void topk_refine(const float* __restrict__ dotPart,
                                                   const unsigned short* __restrict__ Phi,
                                                   const char* __restrict__ Plo,
                                                   const unsigned short* __restrict__ Khi,
                                                   const char* __restrict__ Klo,
                                                   const float* __restrict__ normP,
                                                   const float* __restrict__ normK,
                                                   const int* __restrict__ colidx,
                                                   const int* __restrict__ n0p,
                                                   float* __restrict__ w01,   // [2][N][2]
                                                   int* __restrict__ i01) {   // [2][N][2]
    __shared__ float sAf[C_DIM];     // 16 KB refine A row
    __shared__ float sr_v1[2][4], sr_v2[2][4];
    __shared__ int   sr_s1[2][4], sr_s2[2][4];
    __shared__ int   s_cnt[2];
    __shared__ int   s_cand[2][16];
    __shared__ float s_rcv[16];

    const int row = blockIdx.x;
    const int t   = threadIdx.x;
    const int wave = t >> 6, lane = t & 63;
    const int n0 = *n0p;
    const float nr = normP[row];

    if (t < 2) s_cnt[t] = 0;

    // sum the 8 K-split partials for my 4 slots
    float4 dv = make_float4(0.f, 0.f, 0.f, 0.f);
    #pragma unroll
    for (int z = 0; z < 8; z++) {
        float4 p = *(const float4*)&dotPart[((size_t)z << 20) + (size_t)row * N_TOT + 4 * t];
        dv.x += p.x; dv.y += p.y; dv.z += p.z; dv.w += p.w;
    }

    // coarse cosines for my 4 compacted slots
    float cv[4];
    #pragma unroll
    for (int e = 0; e < 4; e++) {
        int s = 4 * t + e;
        int gj = colidx[s];
        float nb = (s < n0) ? normK[gj] : normP[gj];
        float d  = (e == 0) ? dv.x : (e == 1) ? dv.y : (e == 2) ? dv.z : dv.w;
        cv[e] = d * rsqrtf(nr * nb);
    }

    // single-pass wave-local top-2 per partition (no barriers inside)
    #pragma unroll
    for (int zz = 0; zz < 2; zz++) {
        float v1 = -INFINITY, v2 = -INFINITY;
        int   s1 = 0x7FFFFFFF, s2 = 0x7FFFFFFF;
        #pragma unroll
        for (int e = 0; e < 4; e++) {
            int s = 4 * t + e;
            bool inz = zz ? (s >= n0) : (s < n0);
            if (inz) ins2(cv[e], s, v1, s1, v2, s2);
        }
        #pragma unroll
        for (int off = 32; off > 0; off >>= 1) {
            float o1 = __shfl_xor(v1, off); int q1 = __shfl_xor(s1, off);
            float o2 = __shfl_xor(v2, off); int q2 = __shfl_xor(s2, off);
            ins2(o1, q1, v1, s1, v2, s2);
            ins2(o2, q2, v1, s1, v2, s2);
        }
        if (lane == 0) {
            sr_v1[zz][wave] = v1; sr_s1[zz][wave] = s1;
            sr_v2[zz][wave] = v2; sr_s2[zz][wave] = s2;
        }
    }
    __syncthreads();

    // cross-wave merge (uniform in all threads) + threshold candidate ballot
    float m1z[2], m2z[2]; int b1z[2], b2z[2];
    #pragma unroll
    for (int zz = 0; zz < 2; zz++) {
        float m1 = -INFINITY, m2 = -INFINITY;
        int   b1 = 0x7FFFFFFF, b2 = 0x7FFFFFFF;
        #pragma unroll
        for (int w = 0; w < 4; w++) {
            ins2(sr_v1[zz][w], sr_s1[zz][w], m1, b1, m2, b2);
            ins2(sr_v2[zz][w], sr_s2[zz][w], m1, b1, m2, b2);
        }
        m1z[zz] = m1; m2z[zz] = m2; b1z[zz] = b1; b2z[zz] = b2;
        const float thr = m2 - T_MARGIN;
        #pragma unroll
        for (int e = 0; e < 4; e++) {
            int s = 4 * t + e;
            bool inz = zz ? (s >= n0) : (s < n0);
            if (inz && cv[e] > thr) {
                int idx = atomicAdd(&s_cnt[zz], 1);
                if (idx < 16) s_cand[zz][idx] = s;  // >16 cands: graceful cap
            }
        }
    }
    __syncthreads();

    bool need[2];
    #pragma unroll
    for (int zz = 0; zz < 2; zz++) {
        const int cnt = s_cnt[zz];
        const bool trusted = (cnt == 2) && (m1z[zz] - m2z[zz] > T_MARGIN);
        need[zz] = !trusted;
        if (trusted && t == 0) {
            int base = (zz * N_TOT + row) * 2;
            w01[base]     = m1z[zz];
            w01[base + 1] = m2z[zz];
            i01[base]     = colidx[b1z[zz]];
            i01[base + 1] = colidx[b2z[zz]];
        }
    }

    if (!need[0] && !need[1]) return;

    // reconstruct A row once (shared by both refines)
    {
        const unsigned short* Ah = Phi + (size_t)row * C_DIM;
        const char*           Al = Plo + (size_t)row * C_DIM;
        #pragma unroll
        for (int s = 0; s < 2; s++) {
            int c = t * 16 + s * 8;
            ushort8 hb = *(const ushort8*)&Ah[c];
            schar8  lb = *(const schar8*)&Al[c];
            #pragma unroll
            for (int e = 0; e < 8; e++) sAf[c + e] = h2f(hb[e]) + lo_dec(lb[e], hb[e]);
        }
    }
    __syncthreads();

    const int grp = t >> 5, l32 = t & 31;
    #pragma unroll
    for (int zz = 0; zz < 2; zz++) {
        if (!need[zz]) continue;
        const int cnt = (s_cnt[zz] < 16) ? s_cnt[zz] : 16;
        #pragma unroll
        for (int p = 0; p < 2; p++) {
            if (p == 1 && cnt <= 8) break;          // uniform
            const int q = grp + 8 * p;
            float acc = 0.0f;
            if (q < cnt) {
                const int cs = s_cand[zz][q];
                const int gj = colidx[cs];
                const unsigned short* bh_row = ((cs < n0) ? Khi : Phi) + (size_t)gj * C_DIM;
                const char*           bl_row = ((cs < n0) ? Klo : Plo) + (size_t)gj * C_DIM;
                #pragma unroll 4
                for (int it = 0; it < 16; it++) {
                    int c = it * 256 + l32 * 8;
                    ushort8 hb = *(const ushort8*)&bh_row[c];
                    schar8  lb = *(const schar8*)&bl_row[c];
                    #pragma unroll
                    for (int e = 0; e < 8; e++)
                        acc = fmaf(sAf[c + e], h2f(hb[e]) + lo_dec(lb[e], hb[e]), acc);
                }
            }
            #pragma unroll
            for (int off = 16; off > 0; off >>= 1) acc += __shfl_xor(acc, off);
            if (l32 == 0) s_rcv[q] = acc;
        }
        __syncthreads();

        if (t == 0) {
            float v1 = -INFINITY, v2 = -INFINITY;
            int   j1 = 0x7FFFFFFF, j2 = 0x7FFFFFFF;
            for (int q = 0; q < cnt; q++) {
                int cs = s_cand[zz][q];
                int gj = colidx[cs];
                float nb = (cs < n0) ? normK[gj] : normP[gj];
                float cvx = s_rcv[q] * rsqrtf(nr * nb);
                if (cvx > v1 || (cvx == v1 && gj < j1)) {
                    v2 = v1; j2 = j1; v1 = cvx; j1 = gj;
                } else if (cvx > v2 || (cvx == v2 && gj < j2)) {
                    v2 = cvx; j2 = gj;
                }
            }
            if (j1 == 0x7FFFFFFF) j1 = 0;   // degenerate-partition guard
            if (j2 == 0x7FFFFFFF) j2 = j1;
            int base = (zz * N_TOT + row) * 2;
            w01[base]     = v1;
            w01[base + 1] = v2;
            i01[base]     = j1;
            i01[base + 1] = j2;
        }
        __syncthreads();
    }
}

// ---------------------------------------------------------------------------
// output: inline means->softmax->weights, copy generated & known (float4),
// rtn = weighted gather. grid (4096), block 256.
__global__ __launch_bounds__(256) void output_kernel(const float* __restrict__ G,
                                                     const float* __restrict__ Kn,
                                                     const float* __restrict__ flag,
                                                     const float* __restrict__ w01,
                                                     const int* __restrict__ i01,
                                                     float* __restrict__ out) {
    __shared__ float red[5][4];
    __shared__ float wts[4];
    const int c  = blockIdx.x;
    const int t  = threadIdx.x;
    const int n4 = t * 4;

    float4 fv = *(const float4*)&flag[n4];
    const float fa[4] = {fv.x, fv.y, fv.z, fv.w};

    float pm[5] = {};
    #pragma unroll
    for (int e = 0; e < 4; e++) {
        int n = n4 + e;
        float m = fa[e];
        pm[0] += m;
        pm[1] += m * w01[n * 2 + 0];
        pm[2] += m * w01[n * 2 + 1];
        pm[3] += m * w01[2 * N_TOT + n * 2 + 0];
        pm[4] += m * w01[2 * N_TOT + n * 2 + 1];
    }
    #pragma unroll
    for (int i = 0; i < 5; i++)
        #pragma unroll
        for (int off = 32; off > 0; off >>= 1)
            pm[i] += __shfl_xor(pm[i], off);
    const int wave = t >> 6, lane = t & 63;
    if (lane == 0) {
        #pragma unroll
        for (int i = 0; i < 5; i++) red[i][wave] = pm[i];
    }
    __syncthreads();
    if (t == 0) {
        float tot[5];
        #pragma unroll
        for (int i = 0; i < 5; i++)
            tot[i] = red[i][0] + red[i][1] + red[i][2] + red[i][3];
        float inv = 1.0f / tot[0];
        float mv[4] = {tot[1] * inv, tot[2] * inv, tot[3] * inv, tot[4] * inv};
        float mx = fmaxf(fmaxf(mv[0], mv[1]), fmaxf(mv[2], mv[3]));
        float e[4], s = 0.0f;
        #pragma unroll
        for (int q = 0; q < 4; q++) { e[q] = expf(mv[q] - mx); s += e[q]; }
        #pragma unroll
        for (int q = 0; q < 4; q++) wts[q] = e[q] / s;
    }
    __syncthreads();
    const float w0 = wts[0], w1 = wts[1], w2 = wts[2], w3 = wts[3];

    float4 gv = *(const float4*)&G[c * N_TOT + n4];
    float4 kv = *(const float4*)&Kn[c * N_TOT + n4];
    *(float4*)&out[c * N_TOT + n4] = gv;
    *(float4*)&out[C_DIM * N_TOT + c * N_TOT + n4] = kv;

    float val[4];
    #pragma unroll
    for (int e = 0; e < 4; e++) {
        int n = n4 + e;
        float v = 0.0f;
        if (fa[e] == 1.0f) {
            int c00 = i01[n * 2 + 0];
            int c01 = i01[n * 2 + 1];
            int c10 = i01[2 * N_TOT + n * 2 + 0];
            int c11 = i01[2 * N_TOT + n * 2 + 1];
            v = w0 * Kn[c * N_TOT + c00] + w1 * Kn[c * N_TOT + c01]
              + w2 * G[c * N_TOT + c10]  + w3 * G[c * N_TOT + c11];
        }
        if (n == 0) {
            bool m0 = (flag[0] == 1.0f);
            int c00 = i01[0], c01 = i01[1];
            int c10 = i01[2 * N_TOT], c11 = i01[2 * N_TOT + 1];
            float kn0 = Kn[c * N_TOT];
            float g0  = G[c * N_TOT];
            if (!(m0 && c00 == 0)) v += w0 * kn0;
            if (!(m0 && c01 == 0)) v += w1 * kn0;
            if (!(m0 && c10 == 0)) v += w2 * g0;
            if (!(m0 && c11 == 0)) v += w3 * g0;
        }
        val[e] = v;
    }
    *(float4*)&out[2 * C_DIM * N_TOT + c * N_TOT + n4] =
        make_float4(val[0], val[1], val[2], val[3]);
}

// ---------------------------------------------------------------------------
extern "C" void kernel_launch(void* const* d_in, const int* in_sizes, int n_in,
                              void* d_out, int out_size, void* d_ws, size_t ws_size,
                              hipStream_t stream) {
    const float* G    = (const float*)d_in[0];
    const float* Kn   = (const float*)d_in[1];
    const float* flag = (const float*)d_in[2];
    float* out = (float*)d_out;

    // ws layout (~56 MB; the harness poisons the whole fixed ws allocation
    // regardless, so ws growth is free)
    char* p = (char*)d_ws;
    unsigned short* Phi = (unsigned short*)p;  p += (size_t)N_TOT * C_DIM * 2;  // 8 MB
    unsigned short* Khi = (unsigned short*)p;  p += (size_t)N_TOT * C_DIM * 2;  // 8 MB
    char* Plo = p;                             p += (size_t)N_TOT * C_DIM;      // 4 MB
    char* Klo = p;                             p += (size_t)N_TOT * C_DIM;      // 4 MB
    float* dotPart = (float*)p;                p += (size_t)8 * N_TOT * N_TOT * 4; // 32 MB
    float* normP  = (float*)p;                 p += N_TOT * 4;
    float* normK  = (float*)p;                 p += N_TOT * 4;
    float* w01    = (float*)p;                 p += 4 * N_TOT * 4;
    int*   i01    = (int*)p;                   p += 4 * N_TOT * 4;
    int*   colidx = (int*)p;                   p += N_TOT * 4;
    int*   n0p    = (int*)p;

    // zero only the atomically-accumulated norms (8 KB)
    hipMemsetAsync(normP, 0, 2 * N_TOT * sizeof(float), stream);

    split_norms<<<dim3(64, 16, 2), 256, 0, stream>>>(G, Kn, flag, Phi, Plo, Khi, Klo,
                                                     normP, normK, colidx, n0p);
    gemm_coarse<<<dim3(16, 8, 8), 256, 0, stream>>>(Phi, Khi, colidx, n0p, dotPart);
    topk_refine<<<1024, 256, 0, stream>>>(dotPart, Phi, Plo, Khi, Klo,
                                          normP, normK, colidx, n0p, w01, i01);
    output_kernel<<<4096, 256, 0, stream>>>(G, Kn, flag, w01, i01, out);
}